// Round 2
// baseline (399.082 us; speedup 1.0000x reference)
//
#include <hip/hip_runtime.h>
#include <math.h>

#define D 64

typedef __fp16 fp16x2 __attribute__((ext_vector_type(2)));
typedef _Float16 half8 __attribute__((ext_vector_type(8)));
typedef _Float16 half4v __attribute__((ext_vector_type(4)));
typedef __attribute__((ext_vector_type(4))) float f32x4;

union h8pun { half8 v; fp16x2 h2[4]; };

// ---------------------------------------------------------------------------
// Prep: W1at/W1bt transposes, permuted fp16 W2h, segment boundaries, and
// zero-init of the atomic accumulation buffers (aggb, denom).
// W2h[n][pos] = fp16(W2[pi_inv(pos)][n]),  pi_inv(pos) = (pos>>2) + 16*(pos&3).
__global__ __launch_bounds__(256) void k_prep(const float* __restrict__ W1,
                                              const float* __restrict__ W2,
                                              float* __restrict__ W1at,
                                              float* __restrict__ W1bt,
                                              _Float16* __restrict__ W2h,
                                              const int* __restrict__ seg_ids,
                                              int* __restrict__ start,
                                              float* __restrict__ aggb,
                                              float* __restrict__ denom,
                                              int E, int N) {
    int i = blockIdx.x * 256 + threadIdx.x;
    if (i < 3 * D * D) {
        int mat = i / (D * D), j = i % (D * D);
        if (mat == 0) {
            int r = j >> 6, c = j & 63;
            W1at[c * D + r] = W1[r * D + c];
        } else if (mat == 1) {
            int r = j >> 6, c = j & 63;
            W1bt[c * D + r] = W1[(D + r) * D + c];
        } else {
            int n = j >> 6, pos = j & 63;
            int k = (pos >> 2) + 16 * (pos & 3);   // pi_inv
            W2h[n * D + pos] = (_Float16)W2[k * D + n];
        }
    }
    if (i <= N) {
        int lo = 0, hi = E;
        while (lo < hi) {
            int mid = (lo + hi) >> 1;
            if (seg_ids[mid] < i) lo = mid + 1; else hi = mid;
        }
        start[i] = lo;
    }
    if (i < N) denom[i] = 0.0f;
    if (i < N * D) aggb[i] = 0.0f;
}

// ---------------------------------------------------------------------------
// Combined MFMA row-projection (fp16), both passes in one launch.
// Waves [0, wavesU):   qu row u = [ pi(u2e[u] @ W1a) (64 h) | fp16(u2e[u]) (64 h) ]
// Waves [wavesU, ...): p~[r] = pi(u2e[nodes[r]] @ W1b + b1)
// pi-layout store: lane writes one contiguous half4 per row (coalesced).
__global__ __launch_bounds__(256) void k_proj_both(const float* __restrict__ u2e,
                                                   const int* __restrict__ nodes,
                                                   const float* __restrict__ W1at,
                                                   const float* __restrict__ W1bt,
                                                   const float* __restrict__ b1,
                                                   _Float16* __restrict__ qu,
                                                   _Float16* __restrict__ p,
                                                   int U, int N, int wavesU, int wavesN) {
    int lane = threadIdx.x & 63;
    int m = lane & 15, quad = lane >> 4;
    int wave = (blockIdx.x * blockDim.x + threadIdx.x) >> 6;

    const float* Wt;
    const int* idx;
    const float* bias;
    _Float16* outp;
    _Float16* copyp;
    int R, w0, wstride, ostride;
    if (wave < wavesU) {
        Wt = W1at; idx = nullptr; bias = nullptr; outp = qu; copyp = qu + 64;
        R = U; w0 = wave; wstride = wavesU; ostride = 128;
    } else {
        Wt = W1bt; idx = nodes; bias = b1; outp = p; copyp = nullptr;
        R = N; w0 = wave - wavesU; wstride = wavesN; ostride = 64;
    }

    half8 Bf[2][4];
    float bv[4];
#pragma unroll
    for (int t = 0; t < 4; ++t) {
        int n = m + 16 * t;
        bv[t] = bias ? bias[n] : 0.0f;
#pragma unroll
        for (int kh = 0; kh < 2; ++kh) {
            const float* col = Wt + n * D + kh * 32 + quad * 8;
#pragma unroll
            for (int j = 0; j < 8; ++j) Bf[kh][t][j] = (_Float16)col[j];
        }
    }

    int ngroups = (R + 15) / 16;
    for (int g = w0; g < ngroups; g += wstride) {
        int r_ = g * 16 + m;
        int rs = r_ < R ? r_ : R - 1;
        int src = idx ? idx[rs] : rs;
        const float4* arow = (const float4*)(u2e + (size_t)src * D);
        float4 x0 = arow[quad * 2], x1 = arow[quad * 2 + 1];
        float4 y0 = arow[8 + quad * 2], y1 = arow[8 + quad * 2 + 1];
        h8pun A0, A1;
        A0.h2[0] = __builtin_amdgcn_cvt_pkrtz(x0.x, x0.y);
        A0.h2[1] = __builtin_amdgcn_cvt_pkrtz(x0.z, x0.w);
        A0.h2[2] = __builtin_amdgcn_cvt_pkrtz(x1.x, x1.y);
        A0.h2[3] = __builtin_amdgcn_cvt_pkrtz(x1.z, x1.w);
        A1.h2[0] = __builtin_amdgcn_cvt_pkrtz(y0.x, y0.y);
        A1.h2[1] = __builtin_amdgcn_cvt_pkrtz(y0.z, y0.w);
        A1.h2[2] = __builtin_amdgcn_cvt_pkrtz(y1.x, y1.y);
        A1.h2[3] = __builtin_amdgcn_cvt_pkrtz(y1.z, y1.w);
        if (copyp && r_ < R) {
            *(half8*)(copyp + (size_t)r_ * 128 + quad * 8) = A0.v;
            *(half8*)(copyp + (size_t)r_ * 128 + 32 + quad * 8) = A1.v;
        }
        f32x4 C[4];
#pragma unroll
        for (int t = 0; t < 4; ++t) C[t] = (f32x4){bv[t], bv[t], bv[t], bv[t]};
#pragma unroll
        for (int t = 0; t < 4; ++t) {
            C[t] = __builtin_amdgcn_mfma_f32_16x16x32_f16(A0.v, Bf[0][t], C[t], 0, 0, 0);
            C[t] = __builtin_amdgcn_mfma_f32_16x16x32_f16(A1.v, Bf[1][t], C[t], 0, 0, 0);
        }
        // pi-layout store: position m*4+t holds col m+16t -> one half4 per row.
#pragma unroll
        for (int r = 0; r < 4; ++r) {
            int row = g * 16 + quad * 4 + r;
            if (row < R) {
                half4v hv = {(_Float16)C[0][r], (_Float16)C[1][r],
                             (_Float16)C[2][r], (_Float16)C[3][r]};
                *(half4v*)(outp + (size_t)row * ostride + m * 4) = hv;
            }
        }
    }
}

// ---------------------------------------------------------------------------
// Single edge-parallel pass: logits (fp16 MFMA) + exp (no max subtraction,
// softmax is shift-invariant and logits are O(1)) + segmented aggregation.
// Each wave owns a CONTIGUOUS chunk of edges; since seg_ids is sorted, the
// per-segment partial sums (64-f32 agg vector + denom) live in registers and
// are flushed via atomicAdd only at segment boundaries (~1 per 32 edges).
// The qu table interleaves q-row and u2e-row (256 B) so both gathers per edge
// hit the same block.
__global__ __launch_bounds__(256) void k_edge_agg(const int* __restrict__ neigh_idx,
                                                  const int* __restrict__ seg_ids,
                                                  const _Float16* __restrict__ qu,
                                                  const _Float16* __restrict__ p,
                                                  const _Float16* __restrict__ W2h,
                                                  const float* __restrict__ b2,
                                                  const float* __restrict__ w3,
                                                  const float* __restrict__ b3,
                                                  float* __restrict__ aggb,
                                                  float* __restrict__ denom,
                                                  int E, int chunk) {
    int lane = threadIdx.x & 63;
    int m = lane & 15, quad = lane >> 4;
    int grp = lane >> 3, sub = lane & 7;
    int wave = (blockIdx.x * blockDim.x + threadIdx.x) >> 6;
    long e_beg = (long)wave * chunk;
    if (e_beg >= E) return;
    long e_end = e_beg + chunk;
    if (e_end > E) e_end = E;

    // W2 fragments (fp16, pre-permuted) + biases
    half8 Bf[2][4];
    float b2v[4], w3v[4];
#pragma unroll
    for (int t = 0; t < 4; ++t) {
        int nn = m + 16 * t;
        b2v[t] = b2[nn];
        w3v[t] = w3[nn];
        Bf[0][t] = *(const half8*)(W2h + nn * D + quad * 8);
        Bf[1][t] = *(const half8*)(W2h + nn * D + 32 + quad * 8);
    }
    float b3v = b3[0];
    const half8 hz = {0, 0, 0, 0, 0, 0, 0, 0};

    float acc[8];
#pragma unroll
    for (int j = 0; j < 8; ++j) acc[j] = 0.0f;
    float dsum = 0.0f;
    bool dirty = false;
    int cur_seg = seg_ids[e_beg];

    auto flush = [&]() {
#pragma unroll
        for (int off = 8; off <= 32; off <<= 1) {
#pragma unroll
            for (int j = 0; j < 8; ++j) acc[j] += __shfl_xor(acc[j], off, 64);
            dsum += __shfl_xor(dsum, off, 64);
        }
        if (grp == 0) {
#pragma unroll
            for (int j = 0; j < 8; ++j)
                atomicAdd(&aggb[(size_t)cur_seg * D + sub * 8 + j], acc[j]);
        }
        if (lane == 0) atomicAdd(&denom[cur_seg], dsum);
#pragma unroll
        for (int j = 0; j < 8; ++j) acc[j] = 0.0f;
        dsum = 0.0f;
    };

    for (long e0 = e_beg; e0 < e_end; e0 += 16) {
        long ea = e0 + m;
        long eas = ea < e_end ? ea : e_end - 1;
        int nbra = neigh_idx[eas];
        int sega = seg_ids[eas];
        const half8* qr = (const half8*)(qu + (size_t)nbra * 128);
        const half8* pr = (const half8*)(p + (size_t)sega * D);
        half8 q0 = qr[quad], q1 = qr[quad + 4];
        half8 p0 = pr[quad], p1 = pr[quad + 4];
        half8 A0 = __builtin_elementwise_max(q0 + p0, hz);
        half8 A1 = __builtin_elementwise_max(q1 + p1, hz);
        f32x4 C[4];
#pragma unroll
        for (int t = 0; t < 4; ++t) C[t] = (f32x4){b2v[t], b2v[t], b2v[t], b2v[t]};
#pragma unroll
        for (int t = 0; t < 4; ++t) {
            C[t] = __builtin_amdgcn_mfma_f32_16x16x32_f16(A0, Bf[0][t], C[t], 0, 0, 0);
            C[t] = __builtin_amdgcn_mfma_f32_16x16x32_f16(A1, Bf[1][t], C[t], 0, 0, 0);
        }
        // per-lane partial logits (features m+16t); butterfly over m-group
        float pa[4];
#pragma unroll
        for (int r = 0; r < 4; ++r) {
            float sa = 0.0f;
#pragma unroll
            for (int t = 0; t < 4; ++t) sa += fmaxf(C[t][r], 0.0f) * w3v[t];
            pa[r] = sa;
        }
#pragma unroll
        for (int off = 1; off <= 8; off <<= 1) {
#pragma unroll
            for (int r = 0; r < 4; ++r) pa[r] += __shfl_xor(pa[r], off, 64);
        }
        // ex[r] = exp(logit) of local edge quad*4+r (valid within chunk only)
        float ex[4];
#pragma unroll
        for (int r = 0; r < 4; ++r) {
            long ee = e0 + quad * 4 + r;
            ex[r] = (ee < e_end) ? __expf(pa[r] + b3v) : 0.0f;
        }
        // ---- segmented aggregation: 2 rounds of 8 edges ----
#pragma unroll
        for (int rd = 0; rd < 2; ++rd) {
            int le = rd * 8 + grp;                 // local edge 0..15
            long ee = e0 + le;
            bool valid = ee < e_end;
            int nb = __shfl(nbra, le, 64);
            int sg = __shfl(sega, le, 64);
            int sl = (le >> 2) << 4;               // lane (m=0, quad=le>>2)
            float w0 = __shfl(ex[0], sl, 64);
            float w1 = __shfl(ex[1], sl, 64);
            float w2_ = __shfl(ex[2], sl, 64);
            float w3_ = __shfl(ex[3], sl, 64);
            int rr = grp & 3;
            float w = rr == 0 ? w0 : rr == 1 ? w1 : rr == 2 ? w2_ : w3_;
            if (!valid) w = 0.0f;
            half8 u8 = *(const half8*)(qu + (size_t)nb * 128 + 64 + sub * 8);
            bool match = (!valid) || (sg == cur_seg);
            if (__all(match)) {
#pragma unroll
                for (int j = 0; j < 8; ++j) acc[j] += w * (float)u8[j];
                dsum += w;
                dirty = true;
            } else {
                if (dirty) flush();
                // max seg in this round (valid lanes); those edges stay in regs
                int sgv = valid ? sg : -1;
                int sgmax = sgv;
#pragma unroll
                for (int off = 8; off <= 32; off <<= 1)
                    sgmax = max(sgmax, __shfl_xor(sgmax, off, 64));
                // atomically emit all segs < sgmax present in this round
                bool done = (!valid) || (sg == sgmax);
                while (!__all(done)) {
                    int s0 = done ? 0x7fffffff : sg;
#pragma unroll
                    for (int off = 8; off <= 32; off <<= 1)
                        s0 = min(s0, __shfl_xor(s0, off, 64));
                    bool mine = !done && (sg == s0);
                    float ta[8], td;
#pragma unroll
                    for (int j = 0; j < 8; ++j) ta[j] = mine ? w * (float)u8[j] : 0.0f;
                    td = mine ? w : 0.0f;
#pragma unroll
                    for (int off = 8; off <= 32; off <<= 1) {
#pragma unroll
                        for (int j = 0; j < 8; ++j) ta[j] += __shfl_xor(ta[j], off, 64);
                        td += __shfl_xor(td, off, 64);
                    }
                    if (grp == 0) {
#pragma unroll
                        for (int j = 0; j < 8; ++j)
                            atomicAdd(&aggb[(size_t)s0 * D + sub * 8 + j], ta[j]);
                    }
                    if (lane == 0) atomicAdd(&denom[s0], td);
                    done = done || mine;
                }
                // carry sgmax edges in registers
                bool mine2 = valid && (sg == sgmax);
#pragma unroll
                for (int j = 0; j < 8; ++j) acc[j] = mine2 ? w * (float)u8[j] : 0.0f;
                dsum = mine2 ? w : 0.0f;
                cur_seg = sgmax;
                dirty = __any(mine2);
            }
        }
    }
    if (dirty) flush();
}

// ---------------------------------------------------------------------------
// Normalize: out[n] = agg[n]/denom[n], or own embedding if no neighbors.
__global__ __launch_bounds__(256) void k_norm(const int* __restrict__ nodes,
                                              const float* __restrict__ u2e,
                                              const float* __restrict__ aggb,
                                              const float* __restrict__ denom,
                                              const int* __restrict__ start,
                                              float* __restrict__ out, int N) {
    int i = blockIdx.x * 256 + threadIdx.x;
    if (i >= N * D) return;
    int n = i >> 6, d = i & 63;
    if (start[n + 1] > start[n])
        out[i] = aggb[i] / denom[n];
    else
        out[i] = u2e[(size_t)nodes[n] * D + d];
}

// ---------------------------------------------------------------------------
extern "C" void kernel_launch(void* const* d_in, const int* in_sizes, int n_in,
                              void* d_out, int out_size, void* d_ws, size_t ws_size,
                              hipStream_t stream) {
    const int* nodes = (const int*)d_in[0];
    const int* neigh_idx = (const int*)d_in[1];
    const int* seg_ids = (const int*)d_in[2];
    const float* u2e = (const float*)d_in[3];
    const float* W1 = (const float*)d_in[4];
    const float* b1 = (const float*)d_in[5];
    const float* W2 = (const float*)d_in[6];
    const float* b2 = (const float*)d_in[7];
    const float* w3 = (const float*)d_in[8];
    const float* b3 = (const float*)d_in[9];
    float* out = (float*)d_out;

    int N = in_sizes[0];
    int E = in_sizes[1];
    int U = in_sizes[3] / D;

    char* ws = (char*)d_ws;
    size_t off = 0;
    auto alloc = [&](size_t bytes) {
        void* ptr = ws + off;
        off = (off + bytes + 255) & ~(size_t)255;
        return ptr;
    };
    int* start = (int*)alloc((size_t)(N + 1) * 4);
    float* W1at = (float*)alloc((size_t)D * D * 4);
    float* W1bt = (float*)alloc((size_t)D * D * 4);
    _Float16* W2h = (_Float16*)alloc((size_t)D * D * 2);
    _Float16* qu = (_Float16*)alloc((size_t)U * 128 * 2);   // interleaved q | u2e_h
    _Float16* p = (_Float16*)alloc((size_t)N * D * 2);
    float* aggb = (float*)alloc((size_t)N * D * 4);
    float* denom = (float*)alloc((size_t)N * 4);
    (void)ws_size;

    int prep_n = N * D;                    // covers 3*D*D, N+1, N, N*D
    k_prep<<<(prep_n + 255) / 256, 256, 0, stream>>>(W1, W2, W1at, W1bt, W2h,
                                                     seg_ids, start, aggb, denom, E, N);
    const int wavesU = 4096, wavesN = 1024;
    k_proj_both<<<(wavesU + wavesN) / 4, 256, 0, stream>>>(u2e, nodes, W1at, W1bt, b1,
                                                           qu, p, U, N, wavesU, wavesN);
    const int NW = 2048 * 256 / 64;        // 8192 waves
    int chunk = ((E + NW - 1) / NW + 15) & ~15;
    if (chunk < 16) chunk = 16;
    k_edge_agg<<<2048, 256, 0, stream>>>(neigh_idx, seg_ids, qu, p, W2h,
                                         b2, w3, b3, aggb, denom, E, chunk);
    k_norm<<<(N * D + 255) / 256, 256, 0, stream>>>(nodes, u2e, aggb, denom, start, out, N);
}

// Round 3
// 236.060 us; speedup vs baseline: 1.6906x; 1.6906x over previous
//
#include <hip/hip_runtime.h>
#include <math.h>

#define D 64

typedef __fp16 fp16x2 __attribute__((ext_vector_type(2)));
typedef _Float16 half8 __attribute__((ext_vector_type(8)));
typedef _Float16 half4v __attribute__((ext_vector_type(4)));
typedef __attribute__((ext_vector_type(4))) float f32x4;

union h8pun { half8 v; fp16x2 h2[4]; };

// ---------------------------------------------------------------------------
// Prep: W1at/W1bt transposes, permuted fp16 W2h, segment boundaries, zero denom.
// W2h[n][pos] = fp16(W2[pi_inv(pos)][n]),  pi_inv(pos) = (pos>>2) + 16*(pos&3).
__global__ __launch_bounds__(256) void k_prep(const float* __restrict__ W1,
                                              const float* __restrict__ W2,
                                              float* __restrict__ W1at,
                                              float* __restrict__ W1bt,
                                              _Float16* __restrict__ W2h,
                                              const int* __restrict__ seg_ids,
                                              int* __restrict__ start,
                                              float* __restrict__ denom,
                                              int E, int N) {
    int i = blockIdx.x * 256 + threadIdx.x;
    if (i < 3 * D * D) {
        int mat = i / (D * D), j = i % (D * D);
        if (mat == 0) {
            int r = j >> 6, c = j & 63;
            W1at[c * D + r] = W1[r * D + c];
        } else if (mat == 1) {
            int r = j >> 6, c = j & 63;
            W1bt[c * D + r] = W1[(D + r) * D + c];
        } else {
            int n = j >> 6, pos = j & 63;
            int k = (pos >> 2) + 16 * (pos & 3);   // pi_inv
            W2h[n * D + pos] = (_Float16)W2[k * D + n];
        }
    }
    if (i <= N) {
        int lo = 0, hi = E;
        while (lo < hi) {
            int mid = (lo + hi) >> 1;
            if (seg_ids[mid] < i) lo = mid + 1; else hi = mid;
        }
        start[i] = lo;
    }
    if (i < N) denom[i] = 0.0f;
}

// ---------------------------------------------------------------------------
// Combined MFMA row-projection (fp16), both passes in one launch.
// Waves [0, wavesU):     q~[r] = pi(u2e[r] @ W1a), u2e_h[r] = fp16(u2e[r])
// Waves [wavesU, ...):   p~[r] = pi(u2e[nodes[r]] @ W1b + b1)
// pi-layout store: lane writes one contiguous half4 per row (coalesced 128 B).
__global__ __launch_bounds__(256) void k_proj_both(const float* __restrict__ u2e,
                                                   const int* __restrict__ nodes,
                                                   const float* __restrict__ W1at,
                                                   const float* __restrict__ W1bt,
                                                   const float* __restrict__ b1,
                                                   _Float16* __restrict__ q,
                                                   _Float16* __restrict__ u2e_h,
                                                   _Float16* __restrict__ p,
                                                   int U, int N, int wavesU, int wavesN) {
    int lane = threadIdx.x & 63;
    int m = lane & 15, quad = lane >> 4;
    int wave = (blockIdx.x * blockDim.x + threadIdx.x) >> 6;

    const float* Wt;
    const int* idx;
    const float* bias;
    _Float16* outp;
    _Float16* copyp;
    int R, w0, wstride;
    if (wave < wavesU) {
        Wt = W1at; idx = nullptr; bias = nullptr; outp = q; copyp = u2e_h;
        R = U; w0 = wave; wstride = wavesU;
    } else {
        Wt = W1bt; idx = nodes; bias = b1; outp = p; copyp = nullptr;
        R = N; w0 = wave - wavesU; wstride = wavesN;
    }

    half8 Bf[2][4];
    float bv[4];
#pragma unroll
    for (int t = 0; t < 4; ++t) {
        int n = m + 16 * t;
        bv[t] = bias ? bias[n] : 0.0f;
#pragma unroll
        for (int kh = 0; kh < 2; ++kh) {
            const float* col = Wt + n * D + kh * 32 + quad * 8;
#pragma unroll
            for (int j = 0; j < 8; ++j) Bf[kh][t][j] = (_Float16)col[j];
        }
    }

    int ngroups = (R + 15) / 16;
    for (int g = w0; g < ngroups; g += wstride) {
        int r_ = g * 16 + m;
        int rs = r_ < R ? r_ : R - 1;
        int src = idx ? idx[rs] : rs;
        const float4* arow = (const float4*)(u2e + (size_t)src * D);
        float4 x0 = arow[quad * 2], x1 = arow[quad * 2 + 1];
        float4 y0 = arow[8 + quad * 2], y1 = arow[8 + quad * 2 + 1];
        h8pun A0, A1;
        A0.h2[0] = __builtin_amdgcn_cvt_pkrtz(x0.x, x0.y);
        A0.h2[1] = __builtin_amdgcn_cvt_pkrtz(x0.z, x0.w);
        A0.h2[2] = __builtin_amdgcn_cvt_pkrtz(x1.x, x1.y);
        A0.h2[3] = __builtin_amdgcn_cvt_pkrtz(x1.z, x1.w);
        A1.h2[0] = __builtin_amdgcn_cvt_pkrtz(y0.x, y0.y);
        A1.h2[1] = __builtin_amdgcn_cvt_pkrtz(y0.z, y0.w);
        A1.h2[2] = __builtin_amdgcn_cvt_pkrtz(y1.x, y1.y);
        A1.h2[3] = __builtin_amdgcn_cvt_pkrtz(y1.z, y1.w);
        if (copyp && r_ < R) {
            *(half8*)(copyp + (size_t)r_ * D + quad * 8) = A0.v;
            *(half8*)(copyp + (size_t)r_ * D + 32 + quad * 8) = A1.v;
        }
        f32x4 C[4];
#pragma unroll
        for (int t = 0; t < 4; ++t) C[t] = (f32x4){bv[t], bv[t], bv[t], bv[t]};
#pragma unroll
        for (int t = 0; t < 4; ++t) {
            C[t] = __builtin_amdgcn_mfma_f32_16x16x32_f16(A0.v, Bf[0][t], C[t], 0, 0, 0);
            C[t] = __builtin_amdgcn_mfma_f32_16x16x32_f16(A1.v, Bf[1][t], C[t], 0, 0, 0);
        }
        // pi-layout store: position m*4+t holds col m+16t -> one half4 per row.
#pragma unroll
        for (int r = 0; r < 4; ++r) {
            int row = g * 16 + quad * 4 + r;
            if (row < R) {
                half4v hv = {(_Float16)C[0][r], (_Float16)C[1][r],
                             (_Float16)C[2][r], (_Float16)C[3][r]};
                *(half4v*)(outp + (size_t)row * D + m * 4) = hv;
            }
        }
    }
}

// ---------------------------------------------------------------------------
// Edge kernel: logits via fp16 MFMA (32 edges per wave-iteration), then
// ex = exp(logit + b3) stored to exb (softmax is shift-invariant; logits are
// O(1), so no max subtraction needed -- validated), and per-segment partial
// denominators accumulated via ONE scalar atomicAdd per (wave-iter, segment)
// (seg_ids sorted => ~2 distinct segments per 32 consecutive edges).
__global__ __launch_bounds__(256) void k_edge_ex(const int* __restrict__ neigh_idx,
                                                 const int* __restrict__ seg_ids,
                                                 const _Float16* __restrict__ q,
                                                 const _Float16* __restrict__ p,
                                                 const _Float16* __restrict__ W2h,
                                                 const float* __restrict__ b2,
                                                 const float* __restrict__ w3,
                                                 const float* __restrict__ b3,
                                                 float* __restrict__ exb,
                                                 float* __restrict__ denom, int E) {
    int lane = threadIdx.x & 63;
    int m = lane & 15, quad = lane >> 4;

    half8 Bf[2][4];
    float b2v[4], w3v[4];
#pragma unroll
    for (int t = 0; t < 4; ++t) {
        int n = m + 16 * t;
        b2v[t] = b2[n];
        w3v[t] = w3[n];
        Bf[0][t] = *(const half8*)(W2h + n * D + quad * 8);
        Bf[1][t] = *(const half8*)(W2h + n * D + 32 + quad * 8);
    }
    float b3v = b3[0];
    const half8 hz = {0, 0, 0, 0, 0, 0, 0, 0};

    int ngroups = (E + 31) / 32;
    int wave = (blockIdx.x * blockDim.x + threadIdx.x) >> 6;
    int nwaves = (gridDim.x * blockDim.x) >> 6;
    for (int g = wave; g < ngroups; g += nwaves) {
        int ea = g * 32 + m, eb = ea + 16;
        int eas = ea < E ? ea : E - 1;
        int ebs = eb < E ? eb : E - 1;
        int nbra = neigh_idx[eas], sega = seg_ids[eas];
        int nbrb = neigh_idx[ebs], segb = seg_ids[ebs];
        const half8* qra = (const half8*)(q + (size_t)nbra * D);
        const half8* pra = (const half8*)(p + (size_t)sega * D);
        const half8* qrb = (const half8*)(q + (size_t)nbrb * D);
        const half8* prb = (const half8*)(p + (size_t)segb * D);
        half8 qa0 = qra[quad], qa1 = qra[quad + 4];
        half8 pa0 = pra[quad], pa1 = pra[quad + 4];
        half8 qb0 = qrb[quad], qb1 = qrb[quad + 4];
        half8 pb0 = prb[quad], pb1 = prb[quad + 4];
        half8 Aa0 = __builtin_elementwise_max(qa0 + pa0, hz);
        half8 Aa1 = __builtin_elementwise_max(qa1 + pa1, hz);
        half8 Ab0 = __builtin_elementwise_max(qb0 + pb0, hz);
        half8 Ab1 = __builtin_elementwise_max(qb1 + pb1, hz);
        f32x4 Ca[4], Cb[4];
#pragma unroll
        for (int t = 0; t < 4; ++t) {
            Ca[t] = (f32x4){b2v[t], b2v[t], b2v[t], b2v[t]};
            Cb[t] = Ca[t];
        }
#pragma unroll
        for (int t = 0; t < 4; ++t) {
            Ca[t] = __builtin_amdgcn_mfma_f32_16x16x32_f16(Aa0, Bf[0][t], Ca[t], 0, 0, 0);
            Ca[t] = __builtin_amdgcn_mfma_f32_16x16x32_f16(Aa1, Bf[1][t], Ca[t], 0, 0, 0);
            Cb[t] = __builtin_amdgcn_mfma_f32_16x16x32_f16(Ab0, Bf[0][t], Cb[t], 0, 0, 0);
            Cb[t] = __builtin_amdgcn_mfma_f32_16x16x32_f16(Ab1, Bf[1][t], Cb[t], 0, 0, 0);
        }
        float pa[4], pb[4];
#pragma unroll
        for (int r = 0; r < 4; ++r) {
            float sa = 0.0f, sb = 0.0f;
#pragma unroll
            for (int t = 0; t < 4; ++t) {
                sa += fmaxf(Ca[t][r], 0.0f) * w3v[t];
                sb += fmaxf(Cb[t][r], 0.0f) * w3v[t];
            }
            pa[r] = sa; pb[r] = sb;
        }
#pragma unroll
        for (int off = 1; off <= 8; off <<= 1) {
#pragma unroll
            for (int r = 0; r < 4; ++r) {
                pa[r] += __shfl_xor(pa[r], off, 64);
                pb[r] += __shfl_xor(pb[r], off, 64);
            }
        }
        // ex = exp(logit + b3); mask out-of-range edges to 0
#pragma unroll
        for (int r = 0; r < 4; ++r) {
            int eea = g * 32 + quad * 4 + r;
            pa[r] = eea < E ? __expf(pa[r] + b3v) : 0.0f;
            pb[r] = eea + 16 < E ? __expf(pb[r] + b3v) : 0.0f;
        }
        // store ex (m==0 lane of each quad group owns 4+4 edges)
        if (m == 0) {
            int e0 = g * 32 + quad * 4;
            if (e0 + 3 < E)
                *(float4*)(exb + e0) = make_float4(pa[0], pa[1], pa[2], pa[3]);
            else
#pragma unroll
                for (int r = 0; r < 4; ++r)
                    if (e0 + r < E) exb[e0 + r] = pa[r];
            int e1 = e0 + 16;
            if (e1 + 3 < E)
                *(float4*)(exb + e1) = make_float4(pb[0], pb[1], pb[2], pb[3]);
            else
#pragma unroll
                for (int r = 0; r < 4; ++r)
                    if (e1 + r < E) exb[e1 + r] = pb[r];
        }
        // ---- segmented denom: redistribute so lane l (<32) owns edge g*32+l ----
        int l2 = lane & 31;
        int srcl = ((l2 & 15) >> 2) << 4;   // lane (m=0) of the quad group owning that edge
        float a0 = __shfl(pa[0], srcl, 64), a1 = __shfl(pa[1], srcl, 64);
        float a2 = __shfl(pa[2], srcl, 64), a3 = __shfl(pa[3], srcl, 64);
        float c0 = __shfl(pb[0], srcl, 64), c1 = __shfl(pb[1], srcl, 64);
        float c2 = __shfl(pb[2], srcl, 64), c3 = __shfl(pb[3], srcl, 64);
        int r2 = l2 & 3;
        float exa = r2 == 0 ? a0 : r2 == 1 ? a1 : r2 == 2 ? a2 : a3;
        float exc = r2 == 0 ? c0 : r2 == 1 ? c1 : r2 == 2 ? c2 : c3;
        float exl = l2 < 16 ? exa : exc;
        int sga = __shfl(sega, l2 & 15, 64);
        int sgb = __shfl(segb, l2 & 15, 64);
        int sgl = l2 < 16 ? sga : sgb;
        bool active = (lane < 32) && (g * 32 + l2 < E);
        while (__any(active)) {
            int s0 = active ? sgl : 0x7fffffff;
#pragma unroll
            for (int off = 1; off <= 32; off <<= 1) s0 = min(s0, __shfl_xor(s0, off, 64));
            float c = (active && sgl == s0) ? exl : 0.0f;
#pragma unroll
            for (int off = 1; off <= 32; off <<= 1) c += __shfl_xor(c, off, 64);
            if (lane == 0) atomicAdd(&denom[s0], c);
            if (sgl == s0) active = false;
        }
    }
}

// ---------------------------------------------------------------------------
// Wave per node: single gather-accumulate pass (denominator precomputed).
// 8 lane-groups x 4-deep unroll = 32 neighbor rows in flight per wave.
__global__ __launch_bounds__(256) void k_agg_fast(const int* __restrict__ nodes,
                                                  const int* __restrict__ neigh_idx,
                                                  const float* __restrict__ u2e,
                                                  const _Float16* __restrict__ u2e_h,
                                                  const float* __restrict__ exb,
                                                  const float* __restrict__ denom,
                                                  const int* __restrict__ start,
                                                  float* __restrict__ out, int N) {
    int n = blockIdx.x * 4 + ((int)threadIdx.x >> 6);
    int lane = threadIdx.x & 63;
    if (n >= N) return;
    int s = start[n];
    int t = start[n + 1];
    if (s == t) {  // no neighbors: own embedding (fp32, exact)
        int node = nodes[n];
        out[(size_t)n * D + lane] = u2e[(size_t)node * D + lane];
        return;
    }
    float inv = 1.0f / denom[n];

    int grp = lane >> 3, sub = lane & 7;   // 8 groups of 8 lanes
    float acc[8];
#pragma unroll
    for (int j = 0; j < 8; ++j) acc[j] = 0.0f;
    for (int i = s; i < t; i += 32) {
#pragma unroll
        for (int uu = 0; uu < 4; ++uu) {
            int ii = i + uu * 8 + grp;
            bool v = ii < t;
            int is = v ? ii : s;
            float w = exb[is];
            int nb = neigh_idx[is];
            half8 r = *(const half8*)(u2e_h + (size_t)nb * D + sub * 8);
            if (!v) w = 0.0f;
#pragma unroll
            for (int j = 0; j < 8; ++j) acc[j] += w * (float)r[j];
        }
    }
#pragma unroll
    for (int off = 8; off <= 32; off <<= 1) {
#pragma unroll
        for (int j = 0; j < 8; ++j) acc[j] += __shfl_xor(acc[j], off, 64);
    }
    if (grp == 0) {
        float* o = out + (size_t)n * D + sub * 8;
        *(float4*)o = make_float4(acc[0] * inv, acc[1] * inv, acc[2] * inv, acc[3] * inv);
        *(float4*)(o + 4) = make_float4(acc[4] * inv, acc[5] * inv, acc[6] * inv, acc[7] * inv);
    }
}

// ---------------------------------------------------------------------------
extern "C" void kernel_launch(void* const* d_in, const int* in_sizes, int n_in,
                              void* d_out, int out_size, void* d_ws, size_t ws_size,
                              hipStream_t stream) {
    const int* nodes = (const int*)d_in[0];
    const int* neigh_idx = (const int*)d_in[1];
    const int* seg_ids = (const int*)d_in[2];
    const float* u2e = (const float*)d_in[3];
    const float* W1 = (const float*)d_in[4];
    const float* b1 = (const float*)d_in[5];
    const float* W2 = (const float*)d_in[6];
    const float* b2 = (const float*)d_in[7];
    const float* w3 = (const float*)d_in[8];
    const float* b3 = (const float*)d_in[9];
    float* out = (float*)d_out;

    int N = in_sizes[0];
    int E = in_sizes[1];
    int U = in_sizes[3] / D;

    char* ws = (char*)d_ws;
    size_t off = 0;
    auto alloc = [&](size_t bytes) {
        void* ptr = ws + off;
        off = (off + bytes + 255) & ~(size_t)255;
        return ptr;
    };
    float* exb = (float*)alloc((size_t)E * 4);
    int* start = (int*)alloc((size_t)(N + 1) * 4);
    float* denom = (float*)alloc((size_t)N * 4);
    float* W1at = (float*)alloc((size_t)D * D * 4);
    float* W1bt = (float*)alloc((size_t)D * D * 4);
    _Float16* W2h = (_Float16*)alloc((size_t)D * D * 2);
    _Float16* q = (_Float16*)alloc((size_t)U * D * 2);
    _Float16* p = (_Float16*)alloc((size_t)N * D * 2);
    _Float16* u2e_h = (_Float16*)alloc((size_t)U * D * 2);
    (void)ws_size;

    int prep_n = (N + 1) > 3 * D * D ? (N + 1) : 3 * D * D;
    k_prep<<<(prep_n + 255) / 256, 256, 0, stream>>>(W1, W2, W1at, W1bt, W2h,
                                                     seg_ids, start, denom, E, N);
    const int wavesU = 6144, wavesN = 2048;
    k_proj_both<<<(wavesU + wavesN) / 4, 256, 0, stream>>>(u2e, nodes, W1at, W1bt, b1,
                                                           q, u2e_h, p, U, N, wavesU, wavesN);
    k_edge_ex<<<2048, 256, 0, stream>>>(neigh_idx, seg_ids, q, p, W2h,
                                        b2, w3, b3, exb, denom, E);
    k_agg_fast<<<(N + 3) / 4, 256, 0, stream>>>(nodes, neigh_idx, u2e, u2e_h,
                                                exb, denom, start, out, N);
}

// Round 4
// 223.138 us; speedup vs baseline: 1.7885x; 1.0579x over previous
//
#include <hip/hip_runtime.h>
#include <math.h>

#define D 64

typedef __fp16 fp16x2 __attribute__((ext_vector_type(2)));
typedef _Float16 half8 __attribute__((ext_vector_type(8)));
typedef _Float16 half4v __attribute__((ext_vector_type(4)));
typedef __attribute__((ext_vector_type(4))) float f32x4;

union h8pun { half8 v; fp16x2 h2[4]; };

// ---------------------------------------------------------------------------
// Prep: W1at/W1bt transposes, permuted fp16 W2h, segment boundaries.
// W2h[n][pos] = fp16(W2[pi_inv(pos)][n]),  pi_inv(pos) = (pos>>2) + 16*(pos&3).
__global__ __launch_bounds__(256) void k_prep(const float* __restrict__ W1,
                                              const float* __restrict__ W2,
                                              float* __restrict__ W1at,
                                              float* __restrict__ W1bt,
                                              _Float16* __restrict__ W2h,
                                              const int* __restrict__ seg_ids,
                                              int* __restrict__ start, int E, int N) {
    int i = blockIdx.x * 256 + threadIdx.x;
    if (i < 3 * D * D) {
        int mat = i / (D * D), j = i % (D * D);
        if (mat == 0) {
            int r = j >> 6, c = j & 63;
            W1at[c * D + r] = W1[r * D + c];
        } else if (mat == 1) {
            int r = j >> 6, c = j & 63;
            W1bt[c * D + r] = W1[(D + r) * D + c];
        } else {
            int n = j >> 6, pos = j & 63;
            int k = (pos >> 2) + 16 * (pos & 3);   // pi_inv
            W2h[n * D + pos] = (_Float16)W2[k * D + n];
        }
    }
    if (i <= N) {
        int lo = 0, hi = E;
        while (lo < hi) {
            int mid = (lo + hi) >> 1;
            if (seg_ids[mid] < i) lo = mid + 1; else hi = mid;
        }
        start[i] = lo;
    }
}

// ---------------------------------------------------------------------------
// Combined MFMA row-projection (fp16), both passes in one launch.
// Waves [0, wavesU):     q~[r] = pi(u2e[r] @ W1a), u2e_h[r] = fp16(u2e[r])
// Waves [wavesU, ...):   p~[r] = pi(u2e[nodes[r]] @ W1b + b1)
// pi-layout store: lane writes one contiguous half4 per row (coalesced 128 B).
__global__ __launch_bounds__(256) void k_proj_both(const float* __restrict__ u2e,
                                                   const int* __restrict__ nodes,
                                                   const float* __restrict__ W1at,
                                                   const float* __restrict__ W1bt,
                                                   const float* __restrict__ b1,
                                                   _Float16* __restrict__ q,
                                                   _Float16* __restrict__ u2e_h,
                                                   _Float16* __restrict__ p,
                                                   int U, int N, int wavesU, int wavesN) {
    int lane = threadIdx.x & 63;
    int m = lane & 15, quad = lane >> 4;
    int wave = (blockIdx.x * blockDim.x + threadIdx.x) >> 6;

    const float* Wt;
    const int* idx;
    const float* bias;
    _Float16* outp;
    _Float16* copyp;
    int R, w0, wstride;
    if (wave < wavesU) {
        Wt = W1at; idx = nullptr; bias = nullptr; outp = q; copyp = u2e_h;
        R = U; w0 = wave; wstride = wavesU;
    } else {
        Wt = W1bt; idx = nodes; bias = b1; outp = p; copyp = nullptr;
        R = N; w0 = wave - wavesU; wstride = wavesN;
    }

    half8 Bf[2][4];
    float bv[4];
#pragma unroll
    for (int t = 0; t < 4; ++t) {
        int n = m + 16 * t;
        bv[t] = bias ? bias[n] : 0.0f;
#pragma unroll
        for (int kh = 0; kh < 2; ++kh) {
            const float* col = Wt + n * D + kh * 32 + quad * 8;
#pragma unroll
            for (int j = 0; j < 8; ++j) Bf[kh][t][j] = (_Float16)col[j];
        }
    }

    int ngroups = (R + 15) / 16;
    for (int g = w0; g < ngroups; g += wstride) {
        int r_ = g * 16 + m;
        int rs = r_ < R ? r_ : R - 1;
        int src = idx ? idx[rs] : rs;
        const float4* arow = (const float4*)(u2e + (size_t)src * D);
        float4 x0 = arow[quad * 2], x1 = arow[quad * 2 + 1];
        float4 y0 = arow[8 + quad * 2], y1 = arow[8 + quad * 2 + 1];
        h8pun A0, A1;
        A0.h2[0] = __builtin_amdgcn_cvt_pkrtz(x0.x, x0.y);
        A0.h2[1] = __builtin_amdgcn_cvt_pkrtz(x0.z, x0.w);
        A0.h2[2] = __builtin_amdgcn_cvt_pkrtz(x1.x, x1.y);
        A0.h2[3] = __builtin_amdgcn_cvt_pkrtz(x1.z, x1.w);
        A1.h2[0] = __builtin_amdgcn_cvt_pkrtz(y0.x, y0.y);
        A1.h2[1] = __builtin_amdgcn_cvt_pkrtz(y0.z, y0.w);
        A1.h2[2] = __builtin_amdgcn_cvt_pkrtz(y1.x, y1.y);
        A1.h2[3] = __builtin_amdgcn_cvt_pkrtz(y1.z, y1.w);
        if (copyp && r_ < R) {
            *(half8*)(copyp + (size_t)r_ * D + quad * 8) = A0.v;
            *(half8*)(copyp + (size_t)r_ * D + 32 + quad * 8) = A1.v;
        }
        f32x4 C[4];
#pragma unroll
        for (int t = 0; t < 4; ++t) C[t] = (f32x4){bv[t], bv[t], bv[t], bv[t]};
#pragma unroll
        for (int t = 0; t < 4; ++t) {
            C[t] = __builtin_amdgcn_mfma_f32_16x16x32_f16(A0.v, Bf[0][t], C[t], 0, 0, 0);
            C[t] = __builtin_amdgcn_mfma_f32_16x16x32_f16(A1.v, Bf[1][t], C[t], 0, 0, 0);
        }
        // pi-layout store: position m*4+t holds col m+16t -> one half4 per row.
#pragma unroll
        for (int r = 0; r < 4; ++r) {
            int row = g * 16 + quad * 4 + r;
            if (row < R) {
                half4v hv = {(_Float16)C[0][r], (_Float16)C[1][r],
                             (_Float16)C[2][r], (_Float16)C[3][r]};
                *(half4v*)(outp + (size_t)row * D + m * 4) = hv;
            }
        }
    }
}

// ---------------------------------------------------------------------------
// Edge kernel (R0 structure): logits via fp16 MFMA, 32 edges per
// wave-iteration (two 16-edge A-sets share B-frags), storing
// ex = exp(logit + b3).  Softmax is shift-invariant and logits are O(1),
// so no max subtraction is needed (validated: absmax unchanged).
__global__ __launch_bounds__(256) void k_edge_ex(const int* __restrict__ neigh_idx,
                                                 const int* __restrict__ seg_ids,
                                                 const _Float16* __restrict__ q,
                                                 const _Float16* __restrict__ p,
                                                 const _Float16* __restrict__ W2h,
                                                 const float* __restrict__ b2,
                                                 const float* __restrict__ w3,
                                                 const float* __restrict__ b3,
                                                 float* __restrict__ exb, int E) {
    int lane = threadIdx.x & 63;
    int m = lane & 15, quad = lane >> 4;

    half8 Bf[2][4];
    float b2v[4], w3v[4];
#pragma unroll
    for (int t = 0; t < 4; ++t) {
        int n = m + 16 * t;
        b2v[t] = b2[n];
        w3v[t] = w3[n];
        Bf[0][t] = *(const half8*)(W2h + n * D + quad * 8);
        Bf[1][t] = *(const half8*)(W2h + n * D + 32 + quad * 8);
    }
    float b3v = b3[0];
    const half8 hz = {0, 0, 0, 0, 0, 0, 0, 0};

    int ngroups = (E + 31) / 32;
    int wave = (blockIdx.x * blockDim.x + threadIdx.x) >> 6;
    int nwaves = (gridDim.x * blockDim.x) >> 6;
    for (int g = wave; g < ngroups; g += nwaves) {
        int ea = g * 32 + m, eb = ea + 16;
        int eas = ea < E ? ea : E - 1;
        int ebs = eb < E ? eb : E - 1;
        int nbra = neigh_idx[eas], sega = seg_ids[eas];
        int nbrb = neigh_idx[ebs], segb = seg_ids[ebs];
        const half8* qra = (const half8*)(q + (size_t)nbra * D);
        const half8* pra = (const half8*)(p + (size_t)sega * D);
        const half8* qrb = (const half8*)(q + (size_t)nbrb * D);
        const half8* prb = (const half8*)(p + (size_t)segb * D);
        half8 qa0 = qra[quad], qa1 = qra[quad + 4];
        half8 pa0 = pra[quad], pa1 = pra[quad + 4];
        half8 qb0 = qrb[quad], qb1 = qrb[quad + 4];
        half8 pb0 = prb[quad], pb1 = prb[quad + 4];
        half8 Aa0 = __builtin_elementwise_max(qa0 + pa0, hz);
        half8 Aa1 = __builtin_elementwise_max(qa1 + pa1, hz);
        half8 Ab0 = __builtin_elementwise_max(qb0 + pb0, hz);
        half8 Ab1 = __builtin_elementwise_max(qb1 + pb1, hz);
        f32x4 Ca[4], Cb[4];
#pragma unroll
        for (int t = 0; t < 4; ++t) {
            Ca[t] = (f32x4){b2v[t], b2v[t], b2v[t], b2v[t]};
            Cb[t] = Ca[t];
        }
#pragma unroll
        for (int t = 0; t < 4; ++t) {
            Ca[t] = __builtin_amdgcn_mfma_f32_16x16x32_f16(Aa0, Bf[0][t], Ca[t], 0, 0, 0);
            Ca[t] = __builtin_amdgcn_mfma_f32_16x16x32_f16(Aa1, Bf[1][t], Ca[t], 0, 0, 0);
            Cb[t] = __builtin_amdgcn_mfma_f32_16x16x32_f16(Ab0, Bf[0][t], Cb[t], 0, 0, 0);
            Cb[t] = __builtin_amdgcn_mfma_f32_16x16x32_f16(Ab1, Bf[1][t], Cb[t], 0, 0, 0);
        }
        float pa[4], pb[4];
#pragma unroll
        for (int r = 0; r < 4; ++r) {
            float sa = 0.0f, sb = 0.0f;
#pragma unroll
            for (int t = 0; t < 4; ++t) {
                sa += fmaxf(Ca[t][r], 0.0f) * w3v[t];
                sb += fmaxf(Cb[t][r], 0.0f) * w3v[t];
            }
            pa[r] = sa; pb[r] = sb;
        }
#pragma unroll
        for (int off = 1; off <= 8; off <<= 1) {
#pragma unroll
            for (int r = 0; r < 4; ++r) {
                pa[r] += __shfl_xor(pa[r], off, 64);
                pb[r] += __shfl_xor(pb[r], off, 64);
            }
        }
        // ex = exp(logit + b3) (uniform across m-lanes; transcendental is cheap
        // vs the gathers); store 4+4 contiguous edges from each quad's m==0 lane
        if (m == 0) {
            int e0 = g * 32 + quad * 4;
            if (e0 + 3 < E)
                *(float4*)(exb + e0) = make_float4(__expf(pa[0] + b3v), __expf(pa[1] + b3v),
                                                   __expf(pa[2] + b3v), __expf(pa[3] + b3v));
            else
#pragma unroll
                for (int r = 0; r < 4; ++r)
                    if (e0 + r < E) exb[e0 + r] = __expf(pa[r] + b3v);
            int e1 = e0 + 16;
            if (e1 + 3 < E)
                *(float4*)(exb + e1) = make_float4(__expf(pb[0] + b3v), __expf(pb[1] + b3v),
                                                   __expf(pb[2] + b3v), __expf(pb[3] + b3v));
            else
#pragma unroll
                for (int r = 0; r < 4; ++r)
                    if (e1 + r < E) exb[e1 + r] = __expf(pb[r] + b3v);
        }
    }
}

// ---------------------------------------------------------------------------
// Wave per node: single gather-accumulate pass.  The softmax denominator is
// accumulated IN-REGISTER alongside acc[] (dsum += w), reduced by the same
// butterfly, and applied as 1/dsum at the store -- no extra pass, no atomics.
// 8 lane-groups x 4-deep unroll = 32 neighbor rows in flight per wave.
__global__ __launch_bounds__(256) void k_agg_fast(const int* __restrict__ nodes,
                                                  const int* __restrict__ neigh_idx,
                                                  const float* __restrict__ u2e,
                                                  const _Float16* __restrict__ u2e_h,
                                                  const float* __restrict__ exb,
                                                  const int* __restrict__ start,
                                                  float* __restrict__ out, int N) {
    int n = blockIdx.x * 4 + ((int)threadIdx.x >> 6);
    int lane = threadIdx.x & 63;
    if (n >= N) return;
    int s = start[n];
    int t = start[n + 1];
    if (s == t) {  // no neighbors: own embedding (fp32, exact)
        int node = nodes[n];
        out[(size_t)n * D + lane] = u2e[(size_t)node * D + lane];
        return;
    }

    int grp = lane >> 3, sub = lane & 7;   // 8 groups of 8 lanes
    float acc[8];
#pragma unroll
    for (int j = 0; j < 8; ++j) acc[j] = 0.0f;
    float dsum = 0.0f;
    for (int i = s; i < t; i += 32) {
#pragma unroll
        for (int uu = 0; uu < 4; ++uu) {
            int ii = i + uu * 8 + grp;
            bool v = ii < t;
            int is = v ? ii : s;
            float w = exb[is];
            int nb = neigh_idx[is];
            half8 r = *(const half8*)(u2e_h + (size_t)nb * D + sub * 8);
            if (!v) w = 0.0f;
            dsum += w;
#pragma unroll
            for (int j = 0; j < 8; ++j) acc[j] += w * (float)r[j];
        }
    }
    // butterfly over grp bits: sums acc across the 8 groups; dsum becomes the
    // full denominator (each grp's partial counted once per sub-slice).
#pragma unroll
    for (int off = 8; off <= 32; off <<= 1) {
#pragma unroll
        for (int j = 0; j < 8; ++j) acc[j] += __shfl_xor(acc[j], off, 64);
        dsum += __shfl_xor(dsum, off, 64);
    }
    if (grp == 0) {
        float inv = 1.0f / dsum;
        float* o = out + (size_t)n * D + sub * 8;
        *(float4*)o = make_float4(acc[0] * inv, acc[1] * inv, acc[2] * inv, acc[3] * inv);
        *(float4*)(o + 4) = make_float4(acc[4] * inv, acc[5] * inv, acc[6] * inv, acc[7] * inv);
    }
}

// ---------------------------------------------------------------------------
extern "C" void kernel_launch(void* const* d_in, const int* in_sizes, int n_in,
                              void* d_out, int out_size, void* d_ws, size_t ws_size,
                              hipStream_t stream) {
    const int* nodes = (const int*)d_in[0];
    const int* neigh_idx = (const int*)d_in[1];
    const int* seg_ids = (const int*)d_in[2];
    const float* u2e = (const float*)d_in[3];
    const float* W1 = (const float*)d_in[4];
    const float* b1 = (const float*)d_in[5];
    const float* W2 = (const float*)d_in[6];
    const float* b2 = (const float*)d_in[7];
    const float* w3 = (const float*)d_in[8];
    const float* b3 = (const float*)d_in[9];
    float* out = (float*)d_out;

    int N = in_sizes[0];
    int E = in_sizes[1];
    int U = in_sizes[3] / D;

    char* ws = (char*)d_ws;
    size_t off = 0;
    auto alloc = [&](size_t bytes) {
        void* ptr = ws + off;
        off = (off + bytes + 255) & ~(size_t)255;
        return ptr;
    };
    float* exb = (float*)alloc((size_t)E * 4);
    int* start = (int*)alloc((size_t)(N + 1) * 4);
    float* W1at = (float*)alloc((size_t)D * D * 4);
    float* W1bt = (float*)alloc((size_t)D * D * 4);
    _Float16* W2h = (_Float16*)alloc((size_t)D * D * 2);
    _Float16* q = (_Float16*)alloc((size_t)U * D * 2);
    _Float16* p = (_Float16*)alloc((size_t)N * D * 2);
    _Float16* u2e_h = (_Float16*)alloc((size_t)U * D * 2);
    (void)ws_size;

    int prep_n = (N + 1) > 3 * D * D ? (N + 1) : 3 * D * D;
    k_prep<<<(prep_n + 255) / 256, 256, 0, stream>>>(W1, W2, W1at, W1bt, W2h,
                                                     seg_ids, start, E, N);
    const int wavesU = 6144, wavesN = 2048;
    k_proj_both<<<(wavesU + wavesN) / 4, 256, 0, stream>>>(u2e, nodes, W1at, W1bt, b1,
                                                           q, u2e_h, p, U, N, wavesU, wavesN);
    k_edge_ex<<<2048, 256, 0, stream>>>(neigh_idx, seg_ids, q, p, W2h,
                                        b2, w3, b3, exb, E);
    k_agg_fast<<<(N + 3) / 4, 256, 0, stream>>>(nodes, neigh_idx, u2e, u2e_h,
                                                exb, start, out, N);
}